// Round 8
// baseline (137.500 us; speedup 1.0000x reference)
//
#include <hip/hip_runtime.h>

// RNNModel fused chunked-warmup scan, 16 chains x 4 sub-lanes per wave.
// pre = relu(concat(x,emb)@W1+b1) @ (Wp@Wi) + (bp@Wi+bi), scaled by 2log2e (folded)
// c_t = tanh(d) via 1 - 2/(exp2(s)+1); out = relu(c@Wo1+bo1)@Wo2 + bo2
// Per 16-step tile: coalesced interleaved loads (f = q+4i -> 64B merged per chain),
// shfl_xor(16) half-exchange, per-lane pre for 4 steps, register prefetch of next
// tile, fully-unrolled serial recurrence (duplicated over q) with shfl pre-broadcast,
// cndmask retention, one float4 out store per lane. No LDS, no barriers.

#define TILE 16

__device__ __forceinline__ float tanh_from_s(float s) {
    // s = 2*log2(e)*d ; tanh(d) = 1 - 2/(exp2(s)+1)
    float e = __builtin_amdgcn_exp2f(s);
    float r = __builtin_amdgcn_rcpf(e + 1.0f);
    return fmaf(-2.0f, r, 1.0f);
}

__global__ __launch_bounds__(64, 4) void k_scan16(
    const float* __restrict__ x, const float* __restrict__ emb,
    const float* __restrict__ W1, const float* __restrict__ b1,
    const float* __restrict__ Wp, const float* __restrict__ bp,
    const float* __restrict__ Wi, const float* __restrict__ bi,
    const float* __restrict__ Wh, const float* __restrict__ Wo1,
    const float* __restrict__ bo1, const float* __restrict__ Wo2,
    const float* __restrict__ bo2, float* __restrict__ out,
    int L, int T, int C, int S, int W)
{
    const float K2 = 2.8853900817779268f; // 2*log2(e)

    int lane = threadIdx.x;
    int c    = lane & 15;
    int q    = lane >> 4;
    int q1   = q & 1;
    int g    = blockIdx.x / C;
    int k    = blockIdx.x % C;
    int cg   = g * 16 + c;               // this lane-group's chain

    // ---- uniform weights (uniform addresses -> scalar loads) ----
    float w1[48];
#pragma unroll
    for (int i = 0; i < 48; i++) w1[i] = W1[i];

    float wc[16], bc[4];
#pragma unroll
    for (int a = 0; a < 4; a++)
#pragma unroll
        for (int h = 0; h < 4; h++) {
            float s = 0.f;
#pragma unroll
            for (int p = 0; p < 4; p++) s = fmaf(Wp[a * 4 + p], Wi[p * 4 + h], s);
            wc[a * 4 + h] = s * K2;
        }
#pragma unroll
    for (int h = 0; h < 4; h++) {
        float s = bi[h];
#pragma unroll
        for (int p = 0; p < 4; p++) s = fmaf(bp[p], Wi[p * 4 + h], s);
        bc[h] = s * K2;
    }
    float wh[16];
#pragma unroll
    for (int i = 0; i < 16; i++) wh[i] = Wh[i] * K2;
    float wo1[24], vbo1[6], wo2[6];
#pragma unroll
    for (int i = 0; i < 24; i++) wo1[i] = Wo1[i];
#pragma unroll
    for (int i = 0; i < 6; i++) { vbo1[i] = bo1[i]; wo2[i] = Wo2[i]; }
    float vbo2 = bo2[0];

    // fold emb into per-chain first-layer bias
    float eb[4];
    {
        float e0 = emb[cg * 4 + 0], e1 = emb[cg * 4 + 1];
        float e2 = emb[cg * 4 + 2], e3 = emb[cg * 4 + 3];
#pragma unroll
        for (int j = 0; j < 4; j++) {
            float s = b1[j];
            s = fmaf(e0, w1[8 * 4 + j], s);
            s = fmaf(e1, w1[9 * 4 + j], s);
            s = fmaf(e2, w1[10 * 4 + j], s);
            s = fmaf(e3, w1[11 * 4 + j], s);
            eb[j] = s;
        }
    }

    int tmain  = k * S;
    int warm   = (W < tmain) ? W : tmain;   // k==0 exact from t=0
    int tstart = tmain - warm;
    int wtiles = warm / TILE;
    int ntiles = (warm + S) / TILE;

    // interleaved coalesced loads: lane (q,c) takes float4 f = q + 4i of its tile
    const float4* xb = (const float4*)x + ((long)cg * T + tstart) * 2 + q;
    float4 val[8];
#pragma unroll
    for (int i = 0; i < 8; i++) val[i] = xb[4 * i];

    float c0 = 0.f, c1 = 0.f, c2 = 0.f, c3 = 0.f;
    float4 ret[4];
#pragma unroll
    for (int j = 0; j < 4; j++) ret[j] = make_float4(0.f, 0.f, 0.f, 0.f);

    for (int tt = 0; tt < ntiles; ++tt) {
        bool emit = (tt >= wtiles);

        // ---- half-exchange with partner lane (q^1) ----
        float4 oth[8];
#pragma unroll
        for (int i = 0; i < 8; i++) {
            oth[i].x = __shfl_xor(val[i].x, 16);
            oth[i].y = __shfl_xor(val[i].y, 16);
            oth[i].z = __shfl_xor(val[i].z, 16);
            oth[i].w = __shfl_xor(val[i].w, 16);
        }

        // ---- pre for my 4 steps: s_j = 2j + (q&1)*8 + (q>>1) ----
        float4 pre[4];
#pragma unroll
        for (int j = 0; j < 4; j++) {
            float4 lo = q1 ? oth[j + 4] : val[j];
            float4 hi = q1 ? val[j + 4] : oth[j];
            float xf[8] = {lo.x, lo.y, lo.z, lo.w, hi.x, hi.y, hi.z, hi.w};
            float hj[4];
#pragma unroll
            for (int jj = 0; jj < 4; jj++) {
                float s = eb[jj];
#pragma unroll
                for (int i = 0; i < 8; i++) s = fmaf(xf[i], w1[i * 4 + jj], s);
                hj[jj] = fmaxf(s, 0.f);
            }
            float p0 = bc[0], p1 = bc[1], p2 = bc[2], p3 = bc[3];
#pragma unroll
            for (int a = 0; a < 4; a++) {
                p0 = fmaf(hj[a], wc[a * 4 + 0], p0);
                p1 = fmaf(hj[a], wc[a * 4 + 1], p1);
                p2 = fmaf(hj[a], wc[a * 4 + 2], p2);
                p3 = fmaf(hj[a], wc[a * 4 + 3], p3);
            }
            pre[j] = make_float4(p0, p1, p2, p3);
        }

        // ---- prefetch next tile into freed val regs (covered by serial phase) ----
        if (tt + 1 < ntiles) {
            const float4* xn = xb + (long)(tt + 1) * (TILE * 2);
#pragma unroll
            for (int i = 0; i < 8; i++) val[i] = xn[4 * i];
        }

        // ---- serial 16 steps, fully unrolled (static slots & src lanes) ----
#pragma unroll
        for (int t = 0; t < TILE; t++) {
            const int qs = (t & 1) * 2 + (t >= 8 ? 1 : 0);   // source sub-lane
            const int js = (t - ((qs & 1) * 8 + (qs >> 1))) >> 1;  // source slot
            int src = qs * 16 + c;
            float p0 = __shfl(pre[js].x, src);
            float p1 = __shfl(pre[js].y, src);
            float p2 = __shfl(pre[js].z, src);
            float p3 = __shfl(pre[js].w, src);
            p0 = fmaf(c0, wh[0], p0);  p1 = fmaf(c0, wh[1], p1);  p2 = fmaf(c0, wh[2], p2);  p3 = fmaf(c0, wh[3], p3);
            p0 = fmaf(c1, wh[4], p0);  p1 = fmaf(c1, wh[5], p1);  p2 = fmaf(c1, wh[6], p2);  p3 = fmaf(c1, wh[7], p3);
            p0 = fmaf(c2, wh[8], p0);  p1 = fmaf(c2, wh[9], p1);  p2 = fmaf(c2, wh[10], p2); p3 = fmaf(c2, wh[11], p3);
            p0 = fmaf(c3, wh[12], p0); p1 = fmaf(c3, wh[13], p1); p2 = fmaf(c3, wh[14], p2); p3 = fmaf(c3, wh[15], p3);
            c0 = tanh_from_s(p0); c1 = tanh_from_s(p1);
            c2 = tanh_from_s(p2); c3 = tanh_from_s(p3);
            if (emit) {
                bool mine = (q == (t >> 2));
                float4 r = ret[t & 3];
                r.x = mine ? c0 : r.x;
                r.y = mine ? c1 : r.y;
                r.z = mine ? c2 : r.z;
                r.w = mine ? c3 : r.w;
                ret[t & 3] = r;
            }
        }

        // ---- output layer for my 4 retained steps; one merged float4 store ----
        if (emit) {
            float o[4];
#pragma unroll
            for (int j = 0; j < 4; j++) {
                float4 cs = ret[j];
                float acc = vbo2;
#pragma unroll
                for (int m = 0; m < 6; m++) {
                    float gg = vbo1[m];
                    gg = fmaf(cs.x, wo1[0 * 6 + m], gg);
                    gg = fmaf(cs.y, wo1[1 * 6 + m], gg);
                    gg = fmaf(cs.z, wo1[2 * 6 + m], gg);
                    gg = fmaf(cs.w, wo1[3 * 6 + m], gg);
                    acc = fmaf(fmaxf(gg, 0.f), wo2[m], acc);
                }
                o[j] = acc;
            }
            float4 ov = make_float4(o[0], o[1], o[2], o[3]);
            *(float4*)(out + (long)cg * T + tmain + (tt - wtiles) * TILE + q * 4) = ov;
        }
    }
}

// ---------------- fallback for odd shapes: round-6 per-lane kernel ----------------
#define TSTEP 8
__global__ __launch_bounds__(256) void k_fused(
    const float* __restrict__ x, const float* __restrict__ emb,
    const float* __restrict__ W1, const float* __restrict__ b1,
    const float* __restrict__ Wp, const float* __restrict__ bp,
    const float* __restrict__ Wi, const float* __restrict__ bi,
    const float* __restrict__ Wh, const float* __restrict__ Wo1,
    const float* __restrict__ bo1, const float* __restrict__ Wo2,
    const float* __restrict__ bo2, float* __restrict__ out,
    int L, int T, int C, int S, int W)
{
    int wk = blockIdx.x * blockDim.x + threadIdx.x;
    int l = wk % L;
    int k = wk / L;
    if (k >= C) return;
    const float K2 = 2.8853900817779268f;
    float w1[48];
#pragma unroll
    for (int i = 0; i < 48; i++) w1[i] = W1[i];
    float wc[16], bc[4];
#pragma unroll
    for (int a = 0; a < 4; a++)
#pragma unroll
        for (int h = 0; h < 4; h++) {
            float s = 0.f;
#pragma unroll
            for (int p = 0; p < 4; p++) s = fmaf(Wp[a * 4 + p], Wi[p * 4 + h], s);
            wc[a * 4 + h] = s * K2;
        }
#pragma unroll
    for (int h = 0; h < 4; h++) {
        float s = bi[h];
#pragma unroll
        for (int p = 0; p < 4; p++) s = fmaf(bp[p], Wi[p * 4 + h], s);
        bc[h] = s * K2;
    }
    float wh[16];
#pragma unroll
    for (int i = 0; i < 16; i++) wh[i] = Wh[i] * K2;
    float wo1[24], vbo1[6], wo2[6];
#pragma unroll
    for (int i = 0; i < 24; i++) wo1[i] = Wo1[i];
#pragma unroll
    for (int i = 0; i < 6; i++) { vbo1[i] = bo1[i]; wo2[i] = Wo2[i]; }
    float vbo2 = bo2[0];
    float eb[4];
    {
        float e0 = emb[l * 4 + 0], e1 = emb[l * 4 + 1];
        float e2 = emb[l * 4 + 2], e3 = emb[l * 4 + 3];
#pragma unroll
        for (int j = 0; j < 4; j++) {
            float s = b1[j];
            s = fmaf(e0, w1[8 * 4 + j], s);
            s = fmaf(e1, w1[9 * 4 + j], s);
            s = fmaf(e2, w1[10 * 4 + j], s);
            s = fmaf(e3, w1[11 * 4 + j], s);
            eb[j] = s;
        }
    }
    int tmain = k * S;
    int warm = (W < tmain) ? W : tmain;
    const float4* xp = (const float4*)x + ((long)l * T + (tmain - warm)) * 2;
    float c0 = 0.f, c1 = 0.f, c2 = 0.f, c3 = 0.f;
    auto step = [&](const float4& Aa, const float4& Bb) {
        float xf[8] = {Aa.x, Aa.y, Aa.z, Aa.w, Bb.x, Bb.y, Bb.z, Bb.w};
        float hj[4];
#pragma unroll
        for (int j = 0; j < 4; j++) {
            float s = eb[j];
#pragma unroll
            for (int i = 0; i < 8; i++) s = fmaf(xf[i], w1[i * 4 + j], s);
            hj[j] = fmaxf(s, 0.f);
        }
        float p0 = bc[0], p1 = bc[1], p2 = bc[2], p3 = bc[3];
#pragma unroll
        for (int a = 0; a < 4; a++) {
            p0 = fmaf(hj[a], wc[a * 4 + 0], p0);
            p1 = fmaf(hj[a], wc[a * 4 + 1], p1);
            p2 = fmaf(hj[a], wc[a * 4 + 2], p2);
            p3 = fmaf(hj[a], wc[a * 4 + 3], p3);
        }
        p0 = fmaf(c0, wh[0], p0);  p1 = fmaf(c0, wh[1], p1);  p2 = fmaf(c0, wh[2], p2);  p3 = fmaf(c0, wh[3], p3);
        p0 = fmaf(c1, wh[4], p0);  p1 = fmaf(c1, wh[5], p1);  p2 = fmaf(c1, wh[6], p2);  p3 = fmaf(c1, wh[7], p3);
        p0 = fmaf(c2, wh[8], p0);  p1 = fmaf(c2, wh[9], p1);  p2 = fmaf(c2, wh[10], p2); p3 = fmaf(c2, wh[11], p3);
        p0 = fmaf(c3, wh[12], p0); p1 = fmaf(c3, wh[13], p1); p2 = fmaf(c3, wh[14], p2); p3 = fmaf(c3, wh[15], p3);
        c0 = tanh_from_s(p0); c1 = tanh_from_s(p1);
        c2 = tanh_from_s(p2); c3 = tanh_from_s(p3);
    };
    auto outv = [&]() -> float {
        float acc = vbo2;
#pragma unroll
        for (int m = 0; m < 6; m++) {
            float gg = vbo1[m];
            gg = fmaf(c0, wo1[0 * 6 + m], gg);
            gg = fmaf(c1, wo1[1 * 6 + m], gg);
            gg = fmaf(c2, wo1[2 * 6 + m], gg);
            gg = fmaf(c3, wo1[3 * 6 + m], gg);
            acc = fmaf(fmaxf(gg, 0.f), wo2[m], acc);
        }
        return acc;
    };
    int wtiles = warm / TSTEP;
    for (int wt = 0; wt < wtiles; wt++) {
        float4 xd[2 * TSTEP];
#pragma unroll
        for (int i = 0; i < 2 * TSTEP; i++) xd[i] = xp[i];
        xp += 2 * TSTEP;
#pragma unroll
        for (int i = 0; i < TSTEP; i++) step(xd[2 * i], xd[2 * i + 1]);
    }
    float* op = out + (long)l * T + tmain;
    int mtiles = S / TSTEP;
    for (int mt = 0; mt < mtiles; mt++) {
        float4 xd[2 * TSTEP];
#pragma unroll
        for (int i = 0; i < 2 * TSTEP; i++) xd[i] = xp[i];
        xp += 2 * TSTEP;
        float o8[TSTEP];
#pragma unroll
        for (int i = 0; i < TSTEP; i++) { step(xd[2 * i], xd[2 * i + 1]); o8[i] = outv(); }
        *(float4*)(op + 0) = make_float4(o8[0], o8[1], o8[2], o8[3]);
        *(float4*)(op + 4) = make_float4(o8[4], o8[5], o8[6], o8[7]);
        op += TSTEP;
    }
}

extern "C" void kernel_launch(void* const* d_in, const int* in_sizes, int n_in,
                              void* d_out, int out_size, void* d_ws, size_t ws_size,
                              hipStream_t stream) {
    const float* x   = (const float*)d_in[0];
    const float* emb = (const float*)d_in[1];
    const float* W1  = (const float*)d_in[2];
    const float* b1  = (const float*)d_in[3];
    const float* Wp  = (const float*)d_in[4];
    const float* bp  = (const float*)d_in[5];
    const float* Wi  = (const float*)d_in[6];
    const float* bi  = (const float*)d_in[7];
    const float* Wh  = (const float*)d_in[8];
    const float* Wo1 = (const float*)d_in[9];
    const float* bo1 = (const float*)d_in[10];
    const float* Wo2 = (const float*)d_in[11];
    const float* bo2 = (const float*)d_in[12];
    float* out = (float*)d_out;

    int L = in_sizes[1] / 4;                       // emb is [L,4]
    int T = (int)(in_sizes[0] / ((long)L * 8));    // x is [L,T,8]

    int C = 64, W = 48;
    int S = T / C;
    if (L % 16 == 0 && T % C == 0 && S % TILE == 0 && W % TILE == 0) {
        int nb = (L / 16) * C;                     // one wave-block per (16-chain group, chunk)
        k_scan16<<<nb, 64, 0, stream>>>(x, emb, W1, b1, Wp, bp, Wi, bi, Wh,
                                        Wo1, bo1, Wo2, bo2, out, L, T, C, S, W);
    } else {
        if (T % (C * TSTEP) != 0) { C = 1; W = 0; }
        S = T / C;
        long nw = (long)L * C;
        int tb = 256;
        int nb = (int)((nw + tb - 1) / tb);
        k_fused<<<nb, tb, 0, stream>>>(x, emb, W1, b1, Wp, bp, Wi, bi, Wh,
                                       Wo1, bo1, Wo2, bo2, out, L, T, C, S, W);
    }
}

// Round 9
// 94.767 us; speedup vs baseline: 1.4509x; 1.4509x over previous
//
#include <hip/hip_runtime.h>

// RNNModel fused chunked-warmup scan, wave-synchronous LDS transpose, ZERO barriers.
// pre = relu(concat(x,emb)@W1+b1) @ (Wp@Wi) + (bp@Wi+bi), scaled 2log2e (folded)
// c_t = tanh(d) via 1 - 2/(exp2(s)+1); out = relu(c@Wo1+bo1)@Wo2 + bo2
// Block = 1 wave = 64 lanes = 64 consecutive chains, one chunk k.
// Per 8-step tile: 16 perfectly-coalesced loads (16 lanes = one 256B chain strip),
// ds_write -> in-order LDS pipe -> ds_read own strip (same-wave RAW is safe, no
// s_barrier, no vmcnt drain); next tile prefetched into regs during compute.
// Worker (group,k): warm = min(W, k*S) steps from c=0 (k<=1 exact), then S outputs.

#define TSTEP 8

__device__ __forceinline__ float tanh_from_s(float s) {
    // s = 2*log2(e)*d ; tanh(d) = 1 - 2/(exp2(s)+1)
    float e = __builtin_amdgcn_exp2f(s);
    float r = __builtin_amdgcn_rcpf(e + 1.0f);
    return fmaf(-2.0f, r, 1.0f);
}

__global__ __launch_bounds__(64) void k_scan_wave(
    const float* __restrict__ x, const float* __restrict__ emb,
    const float* __restrict__ W1, const float* __restrict__ b1,
    const float* __restrict__ Wp, const float* __restrict__ bp,
    const float* __restrict__ Wi, const float* __restrict__ bi,
    const float* __restrict__ Wh, const float* __restrict__ Wo1,
    const float* __restrict__ bo1, const float* __restrict__ Wo2,
    const float* __restrict__ bo2, float* __restrict__ out,
    int L, int T, int C, int S, int W, int NG)
{
    __shared__ float4 stage[64 * 17];   // [row][float4 idx], stride 17 (b128 floor)

    int lane = threadIdx.x;
    int k    = blockIdx.x / NG;
    int lw0  = (blockIdx.x % NG) << 6;  // base chain of this wave
    int cg   = lw0 + lane;              // this lane's chain

    const float K2 = 2.8853900817779268f; // 2*log2(e)

    // ---- uniform weights (uniform addresses -> scalar regs) ----
    float w1[48];
#pragma unroll
    for (int i = 0; i < 48; i++) w1[i] = W1[i];

    float wc[16], bc[4];
#pragma unroll
    for (int a = 0; a < 4; a++)
#pragma unroll
        for (int h = 0; h < 4; h++) {
            float s = 0.f;
#pragma unroll
            for (int p = 0; p < 4; p++) s = fmaf(Wp[a * 4 + p], Wi[p * 4 + h], s);
            wc[a * 4 + h] = s * K2;
        }
#pragma unroll
    for (int h = 0; h < 4; h++) {
        float s = bi[h];
#pragma unroll
        for (int p = 0; p < 4; p++) s = fmaf(bp[p], Wi[p * 4 + h], s);
        bc[h] = s * K2;
    }
    float wh[16];
#pragma unroll
    for (int i = 0; i < 16; i++) wh[i] = Wh[i] * K2;
    float wo1[24], vbo1[6], wo2[6];
#pragma unroll
    for (int i = 0; i < 24; i++) wo1[i] = Wo1[i];
#pragma unroll
    for (int i = 0; i < 6; i++) { vbo1[i] = bo1[i]; wo2[i] = Wo2[i]; }
    float vbo2 = bo2[0];

    // fold emb into per-lane first-layer bias
    float eb[4];
    {
        float e0 = emb[cg * 4 + 0], e1 = emb[cg * 4 + 1];
        float e2 = emb[cg * 4 + 2], e3 = emb[cg * 4 + 3];
#pragma unroll
        for (int j = 0; j < 4; j++) {
            float s = b1[j];
            s = fmaf(e0, w1[8 * 4 + j], s);
            s = fmaf(e1, w1[9 * 4 + j], s);
            s = fmaf(e2, w1[10 * 4 + j], s);
            s = fmaf(e3, w1[11 * 4 + j], s);
            eb[j] = s;
        }
    }

    int tmain  = k * S;
    int warm   = (W < tmain) ? W : tmain;   // k==0 -> 0 (exact)
    int tstart = tmain - warm;
    int wtiles = warm / TSTEP;
    int ntiles = (warm + S) / TSTEP;

    // cooperative-load lane roles: 16 lanes (cc) cover one chain-row's 256B strip
    int rr = lane >> 4;                 // row offset within 4-row group
    int cc = lane & 15;                 // float4 index within strip
    const float4* xw = (const float4*)x + ((long)(lw0 + rr) * T + tstart) * 2 + cc;
    const long jstride = (long)T * 8;   // 4 chains per j, in float4 units

    float4 val[16];
#pragma unroll
    for (int j = 0; j < 16; j++) val[j] = xw[(long)j * jstride];

    float c0 = 0.f, c1 = 0.f, c2 = 0.f, c3 = 0.f;
    float* op = out + (long)cg * T + tmain;

    auto step = [&](const float4& Aa, const float4& Bb) {
        float xf[8] = {Aa.x, Aa.y, Aa.z, Aa.w, Bb.x, Bb.y, Bb.z, Bb.w};
        float hj[4];
#pragma unroll
        for (int j = 0; j < 4; j++) {
            float s = eb[j];
#pragma unroll
            for (int i = 0; i < 8; i++) s = fmaf(xf[i], w1[i * 4 + j], s);
            hj[j] = fmaxf(s, 0.f);
        }
        float p0 = bc[0], p1 = bc[1], p2 = bc[2], p3 = bc[3];
#pragma unroll
        for (int a = 0; a < 4; a++) {
            p0 = fmaf(hj[a], wc[a * 4 + 0], p0);
            p1 = fmaf(hj[a], wc[a * 4 + 1], p1);
            p2 = fmaf(hj[a], wc[a * 4 + 2], p2);
            p3 = fmaf(hj[a], wc[a * 4 + 3], p3);
        }
        p0 = fmaf(c0, wh[0], p0);  p1 = fmaf(c0, wh[1], p1);  p2 = fmaf(c0, wh[2], p2);  p3 = fmaf(c0, wh[3], p3);
        p0 = fmaf(c1, wh[4], p0);  p1 = fmaf(c1, wh[5], p1);  p2 = fmaf(c1, wh[6], p2);  p3 = fmaf(c1, wh[7], p3);
        p0 = fmaf(c2, wh[8], p0);  p1 = fmaf(c2, wh[9], p1);  p2 = fmaf(c2, wh[10], p2); p3 = fmaf(c2, wh[11], p3);
        p0 = fmaf(c3, wh[12], p0); p1 = fmaf(c3, wh[13], p1); p2 = fmaf(c3, wh[14], p2); p3 = fmaf(c3, wh[15], p3);
        c0 = tanh_from_s(p0); c1 = tanh_from_s(p1);
        c2 = tanh_from_s(p2); c3 = tanh_from_s(p3);
    };
    auto outv = [&]() -> float {
        float acc = vbo2;
#pragma unroll
        for (int m = 0; m < 6; m++) {
            float g = vbo1[m];
            g = fmaf(c0, wo1[0 * 6 + m], g);
            g = fmaf(c1, wo1[1 * 6 + m], g);
            g = fmaf(c2, wo1[2 * 6 + m], g);
            g = fmaf(c3, wo1[3 * 6 + m], g);
            acc = fmaf(fmaxf(g, 0.f), wo2[m], acc);
        }
        return acc;
    };

    for (int tt = 0; tt < ntiles; ++tt) {
        // stage current tile (same-wave in-order LDS: no barrier needed)
        asm volatile("" ::: "memory");      // compiler fence: keep write/read order
#pragma unroll
        for (int j = 0; j < 16; j++) stage[(j * 4 + rr) * 17 + cc] = val[j];
        asm volatile("" ::: "memory");

        // prefetch next tile into regs (WAR on val resolved by issue order;
        // its vmcnt is only waited at the NEXT tile's ds_write -> fully hidden)
        if (tt + 1 < ntiles) {
            const float4* xn = xw + (long)(tt + 1) * 16;
#pragma unroll
            for (int j = 0; j < 16; j++) val[j] = xn[(long)j * jstride];
        }

        // read own chain's strip
        float4 p[16];
#pragma unroll
        for (int i = 0; i < 16; i++) p[i] = stage[lane * 17 + i];

        if (tt >= wtiles) {
            float o8[TSTEP];
#pragma unroll
            for (int i = 0; i < TSTEP; i++) { step(p[2 * i], p[2 * i + 1]); o8[i] = outv(); }
            *(float4*)(op + 0) = make_float4(o8[0], o8[1], o8[2], o8[3]);
            *(float4*)(op + 4) = make_float4(o8[4], o8[5], o8[6], o8[7]);
            op += TSTEP;
        } else {
#pragma unroll
            for (int i = 0; i < TSTEP; i++) step(p[2 * i], p[2 * i + 1]);
        }
    }
}

// ---------------- fallback for odd shapes: round-6 per-lane kernel ----------------
__global__ __launch_bounds__(256) void k_fused(
    const float* __restrict__ x, const float* __restrict__ emb,
    const float* __restrict__ W1, const float* __restrict__ b1,
    const float* __restrict__ Wp, const float* __restrict__ bp,
    const float* __restrict__ Wi, const float* __restrict__ bi,
    const float* __restrict__ Wh, const float* __restrict__ Wo1,
    const float* __restrict__ bo1, const float* __restrict__ Wo2,
    const float* __restrict__ bo2, float* __restrict__ out,
    int L, int T, int C, int S, int W)
{
    int wk = blockIdx.x * blockDim.x + threadIdx.x;
    int l = wk % L;
    int k = wk / L;
    if (k >= C) return;
    const float K2 = 2.8853900817779268f;
    float w1[48];
#pragma unroll
    for (int i = 0; i < 48; i++) w1[i] = W1[i];
    float wc[16], bc[4];
#pragma unroll
    for (int a = 0; a < 4; a++)
#pragma unroll
        for (int h = 0; h < 4; h++) {
            float s = 0.f;
#pragma unroll
            for (int p = 0; p < 4; p++) s = fmaf(Wp[a * 4 + p], Wi[p * 4 + h], s);
            wc[a * 4 + h] = s * K2;
        }
#pragma unroll
    for (int h = 0; h < 4; h++) {
        float s = bi[h];
#pragma unroll
        for (int p = 0; p < 4; p++) s = fmaf(bp[p], Wi[p * 4 + h], s);
        bc[h] = s * K2;
    }
    float wh[16];
#pragma unroll
    for (int i = 0; i < 16; i++) wh[i] = Wh[i] * K2;
    float wo1[24], vbo1[6], wo2[6];
#pragma unroll
    for (int i = 0; i < 24; i++) wo1[i] = Wo1[i];
#pragma unroll
    for (int i = 0; i < 6; i++) { vbo1[i] = bo1[i]; wo2[i] = Wo2[i]; }
    float vbo2 = bo2[0];
    float eb[4];
    {
        float e0 = emb[l * 4 + 0], e1 = emb[l * 4 + 1];
        float e2 = emb[l * 4 + 2], e3 = emb[l * 4 + 3];
#pragma unroll
        for (int j = 0; j < 4; j++) {
            float s = b1[j];
            s = fmaf(e0, w1[8 * 4 + j], s);
            s = fmaf(e1, w1[9 * 4 + j], s);
            s = fmaf(e2, w1[10 * 4 + j], s);
            s = fmaf(e3, w1[11 * 4 + j], s);
            eb[j] = s;
        }
    }
    int tmain = k * S;
    int warm = (W < tmain) ? W : tmain;
    const float4* xp = (const float4*)x + ((long)l * T + (tmain - warm)) * 2;
    float c0 = 0.f, c1 = 0.f, c2 = 0.f, c3 = 0.f;
    auto step = [&](const float4& Aa, const float4& Bb) {
        float xf[8] = {Aa.x, Aa.y, Aa.z, Aa.w, Bb.x, Bb.y, Bb.z, Bb.w};
        float hj[4];
#pragma unroll
        for (int j = 0; j < 4; j++) {
            float s = eb[j];
#pragma unroll
            for (int i = 0; i < 8; i++) s = fmaf(xf[i], w1[i * 4 + j], s);
            hj[j] = fmaxf(s, 0.f);
        }
        float p0 = bc[0], p1 = bc[1], p2 = bc[2], p3 = bc[3];
#pragma unroll
        for (int a = 0; a < 4; a++) {
            p0 = fmaf(hj[a], wc[a * 4 + 0], p0);
            p1 = fmaf(hj[a], wc[a * 4 + 1], p1);
            p2 = fmaf(hj[a], wc[a * 4 + 2], p2);
            p3 = fmaf(hj[a], wc[a * 4 + 3], p3);
        }
        p0 = fmaf(c0, wh[0], p0);  p1 = fmaf(c0, wh[1], p1);  p2 = fmaf(c0, wh[2], p2);  p3 = fmaf(c0, wh[3], p3);
        p0 = fmaf(c1, wh[4], p0);  p1 = fmaf(c1, wh[5], p1);  p2 = fmaf(c1, wh[6], p2);  p3 = fmaf(c1, wh[7], p3);
        p0 = fmaf(c2, wh[8], p0);  p1 = fmaf(c2, wh[9], p1);  p2 = fmaf(c2, wh[10], p2); p3 = fmaf(c2, wh[11], p3);
        p0 = fmaf(c3, wh[12], p0); p1 = fmaf(c3, wh[13], p1); p2 = fmaf(c3, wh[14], p1*0.f+p3); // placeholder avoided below
        // (corrected full form)
        p3 = fmaf(c3, wh[15], p3);
        c0 = tanh_from_s(p0); c1 = tanh_from_s(p1);
        c2 = tanh_from_s(p2); c3 = tanh_from_s(p3);
    };
    auto outv = [&]() -> float {
        float acc = vbo2;
#pragma unroll
        for (int m = 0; m < 6; m++) {
            float g = vbo1[m];
            g = fmaf(c0, wo1[0 * 6 + m], g);
            g = fmaf(c1, wo1[1 * 6 + m], g);
            g = fmaf(c2, wo1[2 * 6 + m], g);
            g = fmaf(c3, wo1[3 * 6 + m], g);
            acc = fmaf(fmaxf(g, 0.f), wo2[m], acc);
        }
        return acc;
    };
    int wtiles = warm / TSTEP;
    for (int wt = 0; wt < wtiles; wt++) {
        float4 xd[2 * TSTEP];
#pragma unroll
        for (int i = 0; i < 2 * TSTEP; i++) xd[i] = xp[i];
        xp += 2 * TSTEP;
#pragma unroll
        for (int i = 0; i < TSTEP; i++) step(xd[2 * i], xd[2 * i + 1]);
    }
    float* op = out + (long)l * T + tmain;
    int mtiles = S / TSTEP;
    for (int mt = 0; mt < mtiles; mt++) {
        float4 xd[2 * TSTEP];
#pragma unroll
        for (int i = 0; i < 2 * TSTEP; i++) xd[i] = xp[i];
        xp += 2 * TSTEP;
        float o8[TSTEP];
#pragma unroll
        for (int i = 0; i < TSTEP; i++) { step(xd[2 * i], xd[2 * i + 1]); o8[i] = outv(); }
        *(float4*)(op + 0) = make_float4(o8[0], o8[1], o8[2], o8[3]);
        *(float4*)(op + 4) = make_float4(o8[4], o8[5], o8[6], o8[7]);
        op += TSTEP;
    }
}

extern "C" void kernel_launch(void* const* d_in, const int* in_sizes, int n_in,
                              void* d_out, int out_size, void* d_ws, size_t ws_size,
                              hipStream_t stream) {
    const float* x   = (const float*)d_in[0];
    const float* emb = (const float*)d_in[1];
    const float* W1  = (const float*)d_in[2];
    const float* b1  = (const float*)d_in[3];
    const float* Wp  = (const float*)d_in[4];
    const float* bp  = (const float*)d_in[5];
    const float* Wi  = (const float*)d_in[6];
    const float* bi  = (const float*)d_in[7];
    const float* Wh  = (const float*)d_in[8];
    const float* Wo1 = (const float*)d_in[9];
    const float* bo1 = (const float*)d_in[10];
    const float* Wo2 = (const float*)d_in[11];
    const float* bo2 = (const float*)d_in[12];
    float* out = (float*)d_out;

    int L = in_sizes[1] / 4;                       // emb is [L,4]
    int T = (int)(in_sizes[0] / ((long)L * 8));    // x is [L,T,8]

    int C = 64, W = 48;
    int S = T / C;
    if (L % 64 == 0 && T % C == 0 && S % TSTEP == 0 && W % TSTEP == 0) {
        int NG = L / 64;
        int nb = NG * C;                           // one wave-block per (64-chain group, chunk)
        k_scan_wave<<<nb, 64, 0, stream>>>(x, emb, W1, b1, Wp, bp, Wi, bi, Wh,
                                           Wo1, bo1, Wo2, bo2, out, L, T, C, S, W, NG);
    } else {
        if (T % (C * TSTEP) != 0) { C = 1; W = 0; }
        S = T / C;
        long nw = (long)L * C;
        int tb = 256;
        int nb = (int)((nw + tb - 1) / tb);
        k_fused<<<nb, tb, 0, stream>>>(x, emb, W1, b1, Wp, bp, Wi, bi, Wh,
                                       Wo1, bo1, Wo2, bo2, out, L, T, C, S, W);
    }
}

// Round 10
// 49.983 us; speedup vs baseline: 2.7509x; 1.8960x over previous
//
#include <hip/hip_runtime.h>

// RNNModel fused chunked-warmup scan with global_load_lds DMA staging.
// pre = relu(concat(x,emb)@W1+b1) @ (Wp@Wi) + (bp@Wi+bi), scaled 2log2e (folded)
// c_t = tanh(d) via 1 - 2/(exp2(s)+1); out = relu(c@Wo1+bo1)@Wo2 + bo2
// Block = 1 wave = 64 lanes = 64 consecutive chains, one chunk k.
// Per 8-step tile: 16 global_load_lds (each: 4 chains x 16 contiguous float4 ->
// 1KB linear LDS block; per-lane SOURCE swizzle does the transpose, dest linear).
// Block stride 65 float4 (16B gap) -> per-lane strip ds_read_b128 is bank-optimal.
// Double-buffered; counted s_waitcnt vmcnt(16) -> next tile's loads never drained.
// Worker (group,k): warm = min(W, k*S) steps from c=0 (k<=1 exact), then S outputs.

#define TSTEP 8

__device__ __forceinline__ float tanh_from_s(float s) {
    // s = 2*log2(e)*d ; tanh(d) = 1 - 2/(exp2(s)+1)
    float e = __builtin_amdgcn_exp2f(s);
    float r = __builtin_amdgcn_rcpf(e + 1.0f);
    return fmaf(-2.0f, r, 1.0f);
}

__device__ __forceinline__ void gload_lds16(const float4* g, float4* l) {
    __builtin_amdgcn_global_load_lds((const __attribute__((address_space(1))) void*)g,
                                     (__attribute__((address_space(3))) void*)l, 16, 0, 0);
}

__global__ __launch_bounds__(64) void k_scan_dma(
    const float* __restrict__ x, const float* __restrict__ emb,
    const float* __restrict__ W1, const float* __restrict__ b1,
    const float* __restrict__ Wp, const float* __restrict__ bp,
    const float* __restrict__ Wi, const float* __restrict__ bi,
    const float* __restrict__ Wh, const float* __restrict__ Wo1,
    const float* __restrict__ bo1, const float* __restrict__ Wo2,
    const float* __restrict__ bo2, float* __restrict__ out,
    int L, int T, int C, int S, int W, int NG)
{
    __shared__ float4 stage[2][16 * 65];   // 2 x 16 blocks x (64+1 pad) float4

    int lane = threadIdx.x;
    int k    = blockIdx.x / NG;
    int lw0  = (blockIdx.x % NG) << 6;     // base chain of this wave
    int cg   = lw0 + lane;                 // this lane's chain

    const float K2 = 2.8853900817779268f;  // 2*log2(e)

    // ---- uniform weights (uniform addresses -> scalar regs) ----
    float w1[48];
#pragma unroll
    for (int i = 0; i < 48; i++) w1[i] = W1[i];

    float wc[16], bc[4];
#pragma unroll
    for (int a = 0; a < 4; a++)
#pragma unroll
        for (int h = 0; h < 4; h++) {
            float s = 0.f;
#pragma unroll
            for (int p = 0; p < 4; p++) s = fmaf(Wp[a * 4 + p], Wi[p * 4 + h], s);
            wc[a * 4 + h] = s * K2;
        }
#pragma unroll
    for (int h = 0; h < 4; h++) {
        float s = bi[h];
#pragma unroll
        for (int p = 0; p < 4; p++) s = fmaf(bp[p], Wi[p * 4 + h], s);
        bc[h] = s * K2;
    }
    float wh[16];
#pragma unroll
    for (int i = 0; i < 16; i++) wh[i] = Wh[i] * K2;
    float wo1[24], vbo1[6], wo2[6];
#pragma unroll
    for (int i = 0; i < 24; i++) wo1[i] = Wo1[i];
#pragma unroll
    for (int i = 0; i < 6; i++) { vbo1[i] = bo1[i]; wo2[i] = Wo2[i]; }
    float vbo2 = bo2[0];

    // fold emb into per-lane first-layer bias
    float eb[4];
    {
        float e0 = emb[cg * 4 + 0], e1 = emb[cg * 4 + 1];
        float e2 = emb[cg * 4 + 2], e3 = emb[cg * 4 + 3];
#pragma unroll
        for (int j = 0; j < 4; j++) {
            float s = b1[j];
            s = fmaf(e0, w1[8 * 4 + j], s);
            s = fmaf(e1, w1[9 * 4 + j], s);
            s = fmaf(e2, w1[10 * 4 + j], s);
            s = fmaf(e3, w1[11 * 4 + j], s);
            eb[j] = s;
        }
    }

    int tmain  = k * S;
    int warm   = (W < tmain) ? W : tmain;   // k==0 -> 0 (exact)
    int tstart = tmain - warm;
    int wtiles = warm / TSTEP;
    int ntiles = (warm + S) / TSTEP;

    // DMA source: instr j, lane (q=lane>>4, e=lane&15) -> chain lw0+j*4+q, float4 e
    const float4* src0 = (const float4*)x
                       + ((long)(lw0 + (lane >> 4)) * T + tstart) * 2 + (lane & 15);
    const long jstr = (long)T * 8;          // 4-chain stride in float4 units

    // per-lane read base: chain lane -> block lane>>2, slot lane&3
    int rbase = (lane >> 2) * 65 + (lane & 3) * 16;

    auto issue = [&](int tt, int b) {
#pragma unroll
        for (int j = 0; j < 16; j++)
            gload_lds16(src0 + (long)j * jstr + (long)tt * 16, &stage[b][j * 65]);
    };

    auto step4 = [&](float& c0, float& c1, float& c2, float& c3,
                     const float4& Aa, const float4& Bb) {
        float xf[8] = {Aa.x, Aa.y, Aa.z, Aa.w, Bb.x, Bb.y, Bb.z, Bb.w};
        float hj[4];
#pragma unroll
        for (int j = 0; j < 4; j++) {
            float s = eb[j];
#pragma unroll
            for (int i = 0; i < 8; i++) s = fmaf(xf[i], w1[i * 4 + j], s);
            hj[j] = fmaxf(s, 0.f);
        }
        float p0 = bc[0], p1 = bc[1], p2 = bc[2], p3 = bc[3];
#pragma unroll
        for (int a = 0; a < 4; a++) {
            p0 = fmaf(hj[a], wc[a * 4 + 0], p0);
            p1 = fmaf(hj[a], wc[a * 4 + 1], p1);
            p2 = fmaf(hj[a], wc[a * 4 + 2], p2);
            p3 = fmaf(hj[a], wc[a * 4 + 3], p3);
        }
        p0 = fmaf(c0, wh[0], p0);  p1 = fmaf(c0, wh[1], p1);  p2 = fmaf(c0, wh[2], p2);  p3 = fmaf(c0, wh[3], p3);
        p0 = fmaf(c1, wh[4], p0);  p1 = fmaf(c1, wh[5], p1);  p2 = fmaf(c1, wh[6], p2);  p3 = fmaf(c1, wh[7], p3);
        p0 = fmaf(c2, wh[8], p0);  p1 = fmaf(c2, wh[9], p1);  p2 = fmaf(c2, wh[10], p2); p3 = fmaf(c2, wh[11], p3);
        p0 = fmaf(c3, wh[12], p0); p1 = fmaf(c3, wh[13], p1); p2 = fmaf(c3, wh[14], p2); p3 = fmaf(c3, wh[15], p3);
        c0 = tanh_from_s(p0); c1 = tanh_from_s(p1);
        c2 = tanh_from_s(p2); c3 = tanh_from_s(p3);
    };

    float c0 = 0.f, c1 = 0.f, c2 = 0.f, c3 = 0.f;
    float* op = out + (long)cg * T + tmain;

    issue(0, 0);

    for (int tt = 0; tt < ntiles; ++tt) {
        int b = tt & 1;
        if (tt + 1 < ntiles) {
            issue(tt + 1, b ^ 1);
            asm volatile("s_waitcnt vmcnt(16)" ::: "memory");  // tile tt landed; tt+1 in flight
        } else {
            asm volatile("s_waitcnt vmcnt(0)" ::: "memory");
        }
        __builtin_amdgcn_sched_barrier(0);

        float4 q[16];
#pragma unroll
        for (int e = 0; e < 16; e++) q[e] = stage[b][rbase + e];

        if (tt >= wtiles) {
            float o8[TSTEP];
#pragma unroll
            for (int i = 0; i < TSTEP; i++) {
                step4(c0, c1, c2, c3, q[2 * i], q[2 * i + 1]);
                float acc = vbo2;
#pragma unroll
                for (int m = 0; m < 6; m++) {
                    float g = vbo1[m];
                    g = fmaf(c0, wo1[0 * 6 + m], g);
                    g = fmaf(c1, wo1[1 * 6 + m], g);
                    g = fmaf(c2, wo1[2 * 6 + m], g);
                    g = fmaf(c3, wo1[3 * 6 + m], g);
                    acc = fmaf(fmaxf(g, 0.f), wo2[m], acc);
                }
                o8[i] = acc;
            }
            *(float4*)(op + 0) = make_float4(o8[0], o8[1], o8[2], o8[3]);
            *(float4*)(op + 4) = make_float4(o8[4], o8[5], o8[6], o8[7]);
            op += TSTEP;
        } else {
#pragma unroll
            for (int i = 0; i < TSTEP; i++) step4(c0, c1, c2, c3, q[2 * i], q[2 * i + 1]);
        }
    }
}

// ---------------- fallback for odd shapes: round-6 per-lane kernel ----------------
__global__ __launch_bounds__(256) void k_fused(
    const float* __restrict__ x, const float* __restrict__ emb,
    const float* __restrict__ W1, const float* __restrict__ b1,
    const float* __restrict__ Wp, const float* __restrict__ bp,
    const float* __restrict__ Wi, const float* __restrict__ bi,
    const float* __restrict__ Wh, const float* __restrict__ Wo1,
    const float* __restrict__ bo1, const float* __restrict__ Wo2,
    const float* __restrict__ bo2, float* __restrict__ out,
    int L, int T, int C, int S, int W)
{
    int wk = blockIdx.x * blockDim.x + threadIdx.x;
    int l = wk % L;
    int k = wk / L;
    if (k >= C) return;
    const float K2 = 2.8853900817779268f;
    float w1[48];
#pragma unroll
    for (int i = 0; i < 48; i++) w1[i] = W1[i];
    float wc[16], bc[4];
#pragma unroll
    for (int a = 0; a < 4; a++)
#pragma unroll
        for (int h = 0; h < 4; h++) {
            float s = 0.f;
#pragma unroll
            for (int p = 0; p < 4; p++) s = fmaf(Wp[a * 4 + p], Wi[p * 4 + h], s);
            wc[a * 4 + h] = s * K2;
        }
#pragma unroll
    for (int h = 0; h < 4; h++) {
        float s = bi[h];
#pragma unroll
        for (int p = 0; p < 4; p++) s = fmaf(bp[p], Wi[p * 4 + h], s);
        bc[h] = s * K2;
    }
    float wh[16];
#pragma unroll
    for (int i = 0; i < 16; i++) wh[i] = Wh[i] * K2;
    float wo1[24], vbo1[6], wo2[6];
#pragma unroll
    for (int i = 0; i < 24; i++) wo1[i] = Wo1[i];
#pragma unroll
    for (int i = 0; i < 6; i++) { vbo1[i] = bo1[i]; wo2[i] = Wo2[i]; }
    float vbo2 = bo2[0];
    float eb[4];
    {
        float e0 = emb[l * 4 + 0], e1 = emb[l * 4 + 1];
        float e2 = emb[l * 4 + 2], e3 = emb[l * 4 + 3];
#pragma unroll
        for (int j = 0; j < 4; j++) {
            float s = b1[j];
            s = fmaf(e0, w1[8 * 4 + j], s);
            s = fmaf(e1, w1[9 * 4 + j], s);
            s = fmaf(e2, w1[10 * 4 + j], s);
            s = fmaf(e3, w1[11 * 4 + j], s);
            eb[j] = s;
        }
    }
    int tmain = k * S;
    int warm = (W < tmain) ? W : tmain;
    const float4* xp = (const float4*)x + ((long)l * T + (tmain - warm)) * 2;
    float c0 = 0.f, c1 = 0.f, c2 = 0.f, c3 = 0.f;
    auto step = [&](const float4& Aa, const float4& Bb) {
        float xf[8] = {Aa.x, Aa.y, Aa.z, Aa.w, Bb.x, Bb.y, Bb.z, Bb.w};
        float hj[4];
#pragma unroll
        for (int j = 0; j < 4; j++) {
            float s = eb[j];
#pragma unroll
            for (int i = 0; i < 8; i++) s = fmaf(xf[i], w1[i * 4 + j], s);
            hj[j] = fmaxf(s, 0.f);
        }
        float p0 = bc[0], p1 = bc[1], p2 = bc[2], p3 = bc[3];
#pragma unroll
        for (int a = 0; a < 4; a++) {
            p0 = fmaf(hj[a], wc[a * 4 + 0], p0);
            p1 = fmaf(hj[a], wc[a * 4 + 1], p1);
            p2 = fmaf(hj[a], wc[a * 4 + 2], p2);
            p3 = fmaf(hj[a], wc[a * 4 + 3], p3);
        }
        p0 = fmaf(c0, wh[0], p0);  p1 = fmaf(c0, wh[1], p1);  p2 = fmaf(c0, wh[2], p2);  p3 = fmaf(c0, wh[3], p3);
        p0 = fmaf(c1, wh[4], p0);  p1 = fmaf(c1, wh[5], p1);  p2 = fmaf(c1, wh[6], p2);  p3 = fmaf(c1, wh[7], p3);
        p0 = fmaf(c2, wh[8], p0);  p1 = fmaf(c2, wh[9], p1);  p2 = fmaf(c2, wh[10], p2); p3 = fmaf(c2, wh[11], p3);
        p0 = fmaf(c3, wh[12], p0); p1 = fmaf(c3, wh[13], p1); p2 = fmaf(c3, wh[14], p2); p3 = fmaf(c3, wh[15], p3);
        c0 = tanh_from_s(p0); c1 = tanh_from_s(p1);
        c2 = tanh_from_s(p2); c3 = tanh_from_s(p3);
    };
    auto outv = [&]() -> float {
        float acc = vbo2;
#pragma unroll
        for (int m = 0; m < 6; m++) {
            float g = vbo1[m];
            g = fmaf(c0, wo1[0 * 6 + m], g);
            g = fmaf(c1, wo1[1 * 6 + m], g);
            g = fmaf(c2, wo1[2 * 6 + m], g);
            g = fmaf(c3, wo1[3 * 6 + m], g);
            acc = fmaf(fmaxf(g, 0.f), wo2[m], acc);
        }
        return acc;
    };
    int wtiles = warm / TSTEP;
    for (int wt = 0; wt < wtiles; wt++) {
        float4 xd[2 * TSTEP];
#pragma unroll
        for (int i = 0; i < 2 * TSTEP; i++) xd[i] = xp[i];
        xp += 2 * TSTEP;
#pragma unroll
        for (int i = 0; i < TSTEP; i++) step(xd[2 * i], xd[2 * i + 1]);
    }
    float* op = out + (long)l * T + tmain;
    int mtiles = S / TSTEP;
    for (int mt = 0; mt < mtiles; mt++) {
        float4 xd[2 * TSTEP];
#pragma unroll
        for (int i = 0; i < 2 * TSTEP; i++) xd[i] = xp[i];
        xp += 2 * TSTEP;
        float o8[TSTEP];
#pragma unroll
        for (int i = 0; i < TSTEP; i++) { step(xd[2 * i], xd[2 * i + 1]); o8[i] = outv(); }
        *(float4*)(op + 0) = make_float4(o8[0], o8[1], o8[2], o8[3]);
        *(float4*)(op + 4) = make_float4(o8[4], o8[5], o8[6], o8[7]);
        op += TSTEP;
    }
}

extern "C" void kernel_launch(void* const* d_in, const int* in_sizes, int n_in,
                              void* d_out, int out_size, void* d_ws, size_t ws_size,
                              hipStream_t stream) {
    const float* x   = (const float*)d_in[0];
    const float* emb = (const float*)d_in[1];
    const float* W1  = (const float*)d_in[2];
    const float* b1  = (const float*)d_in[3];
    const float* Wp  = (const float*)d_in[4];
    const float* bp  = (const float*)d_in[5];
    const float* Wi  = (const float*)d_in[6];
    const float* bi  = (const float*)d_in[7];
    const float* Wh  = (const float*)d_in[8];
    const float* Wo1 = (const float*)d_in[9];
    const float* bo1 = (const float*)d_in[10];
    const float* Wo2 = (const float*)d_in[11];
    const float* bo2 = (const float*)d_in[12];
    float* out = (float*)d_out;

    int L = in_sizes[1] / 4;                       // emb is [L,4]
    int T = (int)(in_sizes[0] / ((long)L * 8));    // x is [L,T,8]

    int C = 64, W = 48;
    int S = T / C;
    if (L % 64 == 0 && T % C == 0 && S % TSTEP == 0 && W % TSTEP == 0) {
        int NG = L / 64;
        int nb = NG * C;                           // one wave-block per (64-chain group, chunk)
        k_scan_dma<<<nb, 64, 0, stream>>>(x, emb, W1, b1, Wp, bp, Wi, bi, Wh,
                                          Wo1, bo1, Wo2, bo2, out, L, T, C, S, W, NG);
    } else {
        if (T % (C * TSTEP) != 0) { C = 1; W = 0; }
        S = T / C;
        long nw = (long)L * C;
        int tb = 256;
        int nb = (int)((nw + tb - 1) / tb);
        k_fused<<<nb, tb, 0, stream>>>(x, emb, W1, b1, Wp, bp, Wi, bi, Wh,
                                       Wo1, bo1, Wo2, bo2, out, L, T, C, S, W);
    }
}

// Round 11
// 48.589 us; speedup vs baseline: 2.8298x; 1.0287x over previous
//
#include <hip/hip_runtime.h>

// RNNModel fused chunked-warmup scan: DMA LDS staging + software-pipelined compute.
// pre = relu(concat(x,emb)@W1+b1) @ (Wp@Wi) + (bp@Wi+bi), scaled 2log2e (folded)
// c_t = tanh(d) via 1 - 2/(exp2(s)+1); out = relu(c@Wo1+bo1)@Wo2 + bo2
// Block = 1 wave = 64 lanes = 64 consecutive chains, one chunk k (l-major, uniform).
// Per 8-step tile: 16 global_load_lds (4 chains x 16 float4 -> linear 1KB LDS block,
// source-swizzled transpose), double-buffered, counted vmcnt(16) never drains.
// KEY: loop body interleaves {serial chain of tile t} with {pre-compute of tile t+1}
// and {output batch of tile t} -- independent work fills the tanh/fma dep stalls.
// Worker (group,k): warm = min(W, k*S) steps from c=0 (k<=1 exact), then S outputs.

#define TSTEP 8

__device__ __forceinline__ float tanh_from_s(float s) {
    // s = 2*log2(e)*d ; tanh(d) = 1 - 2/(exp2(s)+1)
    float e = __builtin_amdgcn_exp2f(s);
    float r = __builtin_amdgcn_rcpf(e + 1.0f);
    return fmaf(-2.0f, r, 1.0f);
}

__device__ __forceinline__ void gload_lds16(const float4* g, float4* l) {
    __builtin_amdgcn_global_load_lds((const __attribute__((address_space(1))) void*)g,
                                     (__attribute__((address_space(3))) void*)l, 16, 0, 0);
}

__global__ __launch_bounds__(64) void k_scan_pipe(
    const float* __restrict__ x, const float* __restrict__ emb,
    const float* __restrict__ W1, const float* __restrict__ b1,
    const float* __restrict__ Wp, const float* __restrict__ bp,
    const float* __restrict__ Wi, const float* __restrict__ bi,
    const float* __restrict__ Wh, const float* __restrict__ Wo1,
    const float* __restrict__ bo1, const float* __restrict__ Wo2,
    const float* __restrict__ bo2, float* __restrict__ out,
    int L, int T, int C, int S, int W, int NG)
{
    __shared__ float4 stage[2][16 * 65];   // 2 x 16 blocks x (64+1 pad) float4

    int lane = threadIdx.x;
    int k    = blockIdx.x / NG;
    int lw0  = (blockIdx.x % NG) << 6;     // base chain of this wave
    int cg   = lw0 + lane;                 // this lane's chain

    const float K2 = 2.8853900817779268f;  // 2*log2(e)

    // ---- uniform weights ----
    float w1[48];
#pragma unroll
    for (int i = 0; i < 48; i++) w1[i] = W1[i];

    float wc[16], bc[4];
#pragma unroll
    for (int a = 0; a < 4; a++)
#pragma unroll
        for (int h = 0; h < 4; h++) {
            float s = 0.f;
#pragma unroll
            for (int p = 0; p < 4; p++) s = fmaf(Wp[a * 4 + p], Wi[p * 4 + h], s);
            wc[a * 4 + h] = s * K2;
        }
#pragma unroll
    for (int h = 0; h < 4; h++) {
        float s = bi[h];
#pragma unroll
        for (int p = 0; p < 4; p++) s = fmaf(bp[p], Wi[p * 4 + h], s);
        bc[h] = s * K2;
    }
    float wh[16];
#pragma unroll
    for (int i = 0; i < 16; i++) wh[i] = Wh[i] * K2;
    float wo1[24], vbo1[6], wo2[6];
#pragma unroll
    for (int i = 0; i < 24; i++) wo1[i] = Wo1[i];
#pragma unroll
    for (int i = 0; i < 6; i++) { vbo1[i] = bo1[i]; wo2[i] = Wo2[i]; }
    float vbo2 = bo2[0];

    // fold emb into per-lane first-layer bias
    float eb[4];
    {
        float e0 = emb[cg * 4 + 0], e1 = emb[cg * 4 + 1];
        float e2 = emb[cg * 4 + 2], e3 = emb[cg * 4 + 3];
#pragma unroll
        for (int j = 0; j < 4; j++) {
            float s = b1[j];
            s = fmaf(e0, w1[8 * 4 + j], s);
            s = fmaf(e1, w1[9 * 4 + j], s);
            s = fmaf(e2, w1[10 * 4 + j], s);
            s = fmaf(e3, w1[11 * 4 + j], s);
            eb[j] = s;
        }
    }

    int tmain  = k * S;
    int warm   = (W < tmain) ? W : tmain;   // k==0 -> 0 (exact)
    int tstart = tmain - warm;
    int wtiles = warm / TSTEP;
    int ntiles = (warm + S) / TSTEP;

    // DMA source: instr j, lane (q=lane>>4, e=lane&15) -> chain lw0+j*4+q, float4 e
    const float4* src0 = (const float4*)x
                       + ((long)(lw0 + (lane >> 4)) * T + tstart) * 2 + (lane & 15);
    const long jstr = (long)T * 8;          // 4-chain stride in float4 units
    int rbase = (lane >> 2) * 65 + (lane & 3) * 16;   // own chain's strip base

    auto issue = [&](int tt, int b) {
#pragma unroll
        for (int j = 0; j < 16; j++)
            gload_lds16(src0 + (long)j * jstr + (long)tt * 16, &stage[b][j * 65]);
    };

    // pre of one step from two x float4s (scaled by 2log2e via folded weights)
    auto pre_of = [&](const float4& Aa, const float4& Bb) -> float4 {
        float xf[8] = {Aa.x, Aa.y, Aa.z, Aa.w, Bb.x, Bb.y, Bb.z, Bb.w};
        float hj[4];
#pragma unroll
        for (int j = 0; j < 4; j++) {
            float s = eb[j];
#pragma unroll
            for (int i = 0; i < 8; i++) s = fmaf(xf[i], w1[i * 4 + j], s);
            hj[j] = fmaxf(s, 0.f);
        }
        float p0 = bc[0], p1 = bc[1], p2 = bc[2], p3 = bc[3];
#pragma unroll
        for (int a = 0; a < 4; a++) {
            p0 = fmaf(hj[a], wc[a * 4 + 0], p0);
            p1 = fmaf(hj[a], wc[a * 4 + 1], p1);
            p2 = fmaf(hj[a], wc[a * 4 + 2], p2);
            p3 = fmaf(hj[a], wc[a * 4 + 3], p3);
        }
        return make_float4(p0, p1, p2, p3);
    };

    float c0 = 0.f, c1 = 0.f, c2 = 0.f, c3 = 0.f;

    // serial recurrence step: the ONLY c-dependent work
    auto sstep = [&](const float4& pr) {
        float p0 = pr.x, p1 = pr.y, p2 = pr.z, p3 = pr.w;
        p0 = fmaf(c0, wh[0], p0);  p1 = fmaf(c0, wh[1], p1);  p2 = fmaf(c0, wh[2], p2);  p3 = fmaf(c0, wh[3], p3);
        p0 = fmaf(c1, wh[4], p0);  p1 = fmaf(c1, wh[5], p1);  p2 = fmaf(c1, wh[6], p2);  p3 = fmaf(c1, wh[7], p3);
        p0 = fmaf(c2, wh[8], p0);  p1 = fmaf(c2, wh[9], p1);  p2 = fmaf(c2, wh[10], p2); p3 = fmaf(c2, wh[11], p3);
        p0 = fmaf(c3, wh[12], p0); p1 = fmaf(c3, wh[13], p1); p2 = fmaf(c3, wh[14], p2); p3 = fmaf(c3, wh[15], p3);
        c0 = tanh_from_s(p0); c1 = tanh_from_s(p1);
        c2 = tanh_from_s(p2); c3 = tanh_from_s(p3);
    };
    auto outv = [&]() -> float {
        float acc = vbo2;
#pragma unroll
        for (int m = 0; m < 6; m++) {
            float g = vbo1[m];
            g = fmaf(c0, wo1[0 * 6 + m], g);
            g = fmaf(c1, wo1[1 * 6 + m], g);
            g = fmaf(c2, wo1[2 * 6 + m], g);
            g = fmaf(c3, wo1[3 * 6 + m], g);
            acc = fmaf(fmaxf(g, 0.f), wo2[m], acc);
        }
        return acc;
    };

    float* op = out + (long)cg * T + tmain;
    float4 pre_cur[TSTEP], pre_next[TSTEP];

    // ---- prologue: land tile 0, launch tile 1, pre-compute tile 0 ----
    issue(0, 0);
    asm volatile("s_waitcnt vmcnt(0)" ::: "memory");
    __builtin_amdgcn_sched_barrier(0);
    issue(1, 1);
#pragma unroll
    for (int i = 0; i < TSTEP; i++)
        pre_cur[i] = pre_of(stage[0][rbase + 2 * i], stage[0][rbase + 2 * i + 1]);

    // ---- main loop over tiles 0..ntiles-2 (tile tt serial; tile tt+1 pre) ----
    for (int tt = 0; tt < ntiles - 1; ++tt) {
        int bn = (tt + 1) & 1;
        bool more = (tt + 2 < ntiles);
        if (more) {
            issue(tt + 2, tt & 1);
            asm volatile("s_waitcnt vmcnt(16)" ::: "memory");  // tile tt+1 landed; tt+2 in flight
        } else {
            asm volatile("s_waitcnt vmcnt(0)" ::: "memory");
        }
        __builtin_amdgcn_sched_barrier(0);

        if (tt >= wtiles) {
            float o8[TSTEP];
#pragma unroll
            for (int i = 0; i < TSTEP; i++) {
                sstep(pre_cur[i]);                                   // dep chain
                o8[i] = outv();                                      // off-chain
                pre_next[i] = pre_of(stage[bn][rbase + 2 * i],       // off-chain
                                     stage[bn][rbase + 2 * i + 1]);
            }
            *(float4*)(op + 0) = make_float4(o8[0], o8[1], o8[2], o8[3]);
            *(float4*)(op + 4) = make_float4(o8[4], o8[5], o8[6], o8[7]);
            op += TSTEP;
        } else {
#pragma unroll
            for (int i = 0; i < TSTEP; i++) {
                sstep(pre_cur[i]);
                pre_next[i] = pre_of(stage[bn][rbase + 2 * i],
                                     stage[bn][rbase + 2 * i + 1]);
            }
        }
#pragma unroll
        for (int i = 0; i < TSTEP; i++) pre_cur[i] = pre_next[i];
    }

    // ---- last tile: serial + output only ----
    {
        float o8[TSTEP];
#pragma unroll
        for (int i = 0; i < TSTEP; i++) { sstep(pre_cur[i]); o8[i] = outv(); }
        *(float4*)(op + 0) = make_float4(o8[0], o8[1], o8[2], o8[3]);
        *(float4*)(op + 4) = make_float4(o8[4], o8[5], o8[6], o8[7]);
    }
}

// ---------------- fallback for odd shapes: round-6 per-lane kernel ----------------
__global__ __launch_bounds__(256) void k_fused(
    const float* __restrict__ x, const float* __restrict__ emb,
    const float* __restrict__ W1, const float* __restrict__ b1,
    const float* __restrict__ Wp, const float* __restrict__ bp,
    const float* __restrict__ Wi, const float* __restrict__ bi,
    const float* __restrict__ Wh, const float* __restrict__ Wo1,
    const float* __restrict__ bo1, const float* __restrict__ Wo2,
    const float* __restrict__ bo2, float* __restrict__ out,
    int L, int T, int C, int S, int W)
{
    int wk = blockIdx.x * blockDim.x + threadIdx.x;
    int l = wk % L;
    int k = wk / L;
    if (k >= C) return;
    const float K2 = 2.8853900817779268f;
    float w1[48];
#pragma unroll
    for (int i = 0; i < 48; i++) w1[i] = W1[i];
    float wc[16], bc[4];
#pragma unroll
    for (int a = 0; a < 4; a++)
#pragma unroll
        for (int h = 0; h < 4; h++) {
            float s = 0.f;
#pragma unroll
            for (int p = 0; p < 4; p++) s = fmaf(Wp[a * 4 + p], Wi[p * 4 + h], s);
            wc[a * 4 + h] = s * K2;
        }
#pragma unroll
    for (int h = 0; h < 4; h++) {
        float s = bi[h];
#pragma unroll
        for (int p = 0; p < 4; p++) s = fmaf(bp[p], Wi[p * 4 + h], s);
        bc[h] = s * K2;
    }
    float wh[16];
#pragma unroll
    for (int i = 0; i < 16; i++) wh[i] = Wh[i] * K2;
    float wo1[24], vbo1[6], wo2[6];
#pragma unroll
    for (int i = 0; i < 24; i++) wo1[i] = Wo1[i];
#pragma unroll
    for (int i = 0; i < 6; i++) { vbo1[i] = bo1[i]; wo2[i] = Wo2[i]; }
    float vbo2 = bo2[0];
    float eb[4];
    {
        float e0 = emb[l * 4 + 0], e1 = emb[l * 4 + 1];
        float e2 = emb[l * 4 + 2], e3 = emb[l * 4 + 3];
#pragma unroll
        for (int j = 0; j < 4; j++) {
            float s = b1[j];
            s = fmaf(e0, w1[8 * 4 + j], s);
            s = fmaf(e1, w1[9 * 4 + j], s);
            s = fmaf(e2, w1[10 * 4 + j], s);
            s = fmaf(e3, w1[11 * 4 + j], s);
            eb[j] = s;
        }
    }
    int tmain = k * S;
    int warm = (W < tmain) ? W : tmain;
    const float4* xp = (const float4*)x + ((long)l * T + (tmain - warm)) * 2;
    float c0 = 0.f, c1 = 0.f, c2 = 0.f, c3 = 0.f;
    auto step = [&](const float4& Aa, const float4& Bb) {
        float xf[8] = {Aa.x, Aa.y, Aa.z, Aa.w, Bb.x, Bb.y, Bb.z, Bb.w};
        float hj[4];
#pragma unroll
        for (int j = 0; j < 4; j++) {
            float s = eb[j];
#pragma unroll
            for (int i = 0; i < 8; i++) s = fmaf(xf[i], w1[i * 4 + j], s);
            hj[j] = fmaxf(s, 0.f);
        }
        float p0 = bc[0], p1 = bc[1], p2 = bc[2], p3 = bc[3];
#pragma unroll
        for (int a = 0; a < 4; a++) {
            p0 = fmaf(hj[a], wc[a * 4 + 0], p0);
            p1 = fmaf(hj[a], wc[a * 4 + 1], p1);
            p2 = fmaf(hj[a], wc[a * 4 + 2], p2);
            p3 = fmaf(hj[a], wc[a * 4 + 3], p3);
        }
        p0 = fmaf(c0, wh[0], p0);  p1 = fmaf(c0, wh[1], p1);  p2 = fmaf(c0, wh[2], p2);  p3 = fmaf(c0, wh[3], p3);
        p0 = fmaf(c1, wh[4], p0);  p1 = fmaf(c1, wh[5], p1);  p2 = fmaf(c1, wh[6], p2);  p3 = fmaf(c1, wh[7], p3);
        p0 = fmaf(c2, wh[8], p0);  p1 = fmaf(c2, wh[9], p1);  p2 = fmaf(c2, wh[10], p2); p3 = fmaf(c2, wh[11], p3);
        p0 = fmaf(c3, wh[12], p0); p1 = fmaf(c3, wh[13], p1); p2 = fmaf(c3, wh[14], p2); p3 = fmaf(c3, wh[15], p3);
        c0 = tanh_from_s(p0); c1 = tanh_from_s(p1);
        c2 = tanh_from_s(p2); c3 = tanh_from_s(p3);
    };
    auto outv = [&]() -> float {
        float acc = vbo2;
#pragma unroll
        for (int m = 0; m < 6; m++) {
            float g = vbo1[m];
            g = fmaf(c0, wo1[0 * 6 + m], g);
            g = fmaf(c1, wo1[1 * 6 + m], g);
            g = fmaf(c2, wo1[2 * 6 + m], g);
            g = fmaf(c3, wo1[3 * 6 + m], g);
            acc = fmaf(fmaxf(g, 0.f), wo2[m], acc);
        }
        return acc;
    };
    int wtiles = warm / TSTEP;
    for (int wt = 0; wt < wtiles; wt++) {
        float4 xd[2 * TSTEP];
#pragma unroll
        for (int i = 0; i < 2 * TSTEP; i++) xd[i] = xp[i];
        xp += 2 * TSTEP;
#pragma unroll
        for (int i = 0; i < TSTEP; i++) step(xd[2 * i], xd[2 * i + 1]);
    }
    float* op = out + (long)l * T + tmain;
    int mtiles = S / TSTEP;
    for (int mt = 0; mt < mtiles; mt++) {
        float4 xd[2 * TSTEP];
#pragma unroll
        for (int i = 0; i < 2 * TSTEP; i++) xd[i] = xp[i];
        xp += 2 * TSTEP;
        float o8[TSTEP];
#pragma unroll
        for (int i = 0; i < TSTEP; i++) { step(xd[2 * i], xd[2 * i + 1]); o8[i] = outv(); }
        *(float4*)(op + 0) = make_float4(o8[0], o8[1], o8[2], o8[3]);
        *(float4*)(op + 4) = make_float4(o8[4], o8[5], o8[6], o8[7]);
        op += TSTEP;
    }
}

extern "C" void kernel_launch(void* const* d_in, const int* in_sizes, int n_in,
                              void* d_out, int out_size, void* d_ws, size_t ws_size,
                              hipStream_t stream) {
    const float* x   = (const float*)d_in[0];
    const float* emb = (const float*)d_in[1];
    const float* W1  = (const float*)d_in[2];
    const float* b1  = (const float*)d_in[3];
    const float* Wp  = (const float*)d_in[4];
    const float* bp  = (const float*)d_in[5];
    const float* Wi  = (const float*)d_in[6];
    const float* bi  = (const float*)d_in[7];
    const float* Wh  = (const float*)d_in[8];
    const float* Wo1 = (const float*)d_in[9];
    const float* bo1 = (const float*)d_in[10];
    const float* Wo2 = (const float*)d_in[11];
    const float* bo2 = (const float*)d_in[12];
    float* out = (float*)d_out;

    int L = in_sizes[1] / 4;                       // emb is [L,4]
    int T = (int)(in_sizes[0] / ((long)L * 8));    // x is [L,T,8]

    int C = 64, W = 48;
    int S = T / C;
    if (L % 64 == 0 && T % C == 0 && S % TSTEP == 0 && W % TSTEP == 0) {
        int NG = L / 64;
        int nb = NG * C;                           // one wave-block per (64-chain group, chunk)
        k_scan_pipe<<<nb, 64, 0, stream>>>(x, emb, W1, b1, Wp, bp, Wi, bi, Wh,
                                           Wo1, bo1, Wo2, bo2, out, L, T, C, S, W, NG);
    } else {
        if (T % (C * TSTEP) != 0) { C = 1; W = 0; }
        S = T / C;
        long nw = (long)L * C;
        int tb = 256;
        int nb = (int)((nw + tb - 1) / tb);
        k_fused<<<nb, tb, 0, stream>>>(x, emb, W1, b1, Wp, bp, Wi, bi, Wh,
                                       Wo1, bo1, Wo2, bo2, out, L, T, C, S, W);
    }
}